// Round 14
// baseline (198.440 us; speedup 1.0000x reference)
//
#include <hip/hip_runtime.h>

#define BB 2
#define NN 1024
#define FF 128
#define H1 64
#define H2 32
#define XPAD 136  // x-row stride in f16 (128+8)
#define PAD 72    // p-row stride in f16 (64+8)
#define REPS 16   // INSTRUMENTATION: phase-B repeat (idempotent stores)

typedef __attribute__((ext_vector_type(4))) _Float16 half4;   // 4 f16 (8B)
typedef __attribute__((ext_vector_type(8))) _Float16 half8;   // 8 f16 (4 VGPR)
typedef __attribute__((ext_vector_type(16))) float f32x16;    // 32x32 MFMA acc
typedef __attribute__((ext_vector_type(2))) float f32x2;      // v_pk_*_f32

// e = relu(a + b) in packed f16: 4x v_pk_add_f16 + 4x v_pk_max_f16
__device__ inline half8 addrelu8(half8 a, half8 b) {
    half8 s = a + b;
    const half8 z = {};
    return __builtin_elementwise_max(s, z);
}

// ---------------------------------------------------------------------------
// INSTRUMENTATION ROUND (R14) on the v6 (R13) kernel. Three phase-B theories
// are dead (R10 inst diet -1.0, R11 reorder -0.4, R13 launch_bounds -0.2)
// and the kernel's own counters have been invisible since R9 (old 4-wave
// config). Phase B repeated REPS=16x: per-rep asm memory clobber + "+v" qj
// touches defeat cross-rep CSE/DCE (rule #17); stores idempotent.
//   B = (dur16 - 22.8)/15;  A+stage+fixed = 22.8 - B.
// Counters of interest: VGPR_Count under (512,2) — did R13's knob even
// change allocation? — VALUBusy vs MfmaUtil, SQ_LDS_BANK_CONFLICT.
// R13 (REPS=1) remains the recoverable best at 22.8us.
// ---------------------------------------------------------------------------
__global__ __launch_bounds__(512, 2) void fused_kernel(
    const float* __restrict__ x, const float* __restrict__ W1,
    const float* __restrict__ b1, const float* __restrict__ W2,
    const float* __restrict__ b2, const float* __restrict__ W3,
    const float* __restrict__ b3, float* __restrict__ out)
{
    __shared__ __align__(16) _Float16 xlds[128][XPAD];  // 34.8 KB staged x
    __shared__ __align__(16) _Float16 plds[64][PAD];    // 9.2 KB pib rows
    __shared__ __align__(16) _Float16 pjlds[64][PAD];   // 9.2 KB pj rows

    const int tid  = threadIdx.x;
    const int lane = tid & 63;
    const int wv   = tid >> 6;                // 0..7
    const int bid  = blockIdx.x;

    const int b   = bid >> 8;                 // 256 blocks per batch
    const int rem = bid & 255;
    const int i0  = (rem >> 4) * 64;          // 16 i-tiles (64 rows each)
    const int j0  = (rem & 15) * 64;          // 16 j-tiles (64 cols each)
    const int jn  = lane & 31;                // m/n lane index
    const int hi  = lane >> 5;                // k-group half
    const int m   = jn;

    // ============ stage: 128 x-rows -> xlds (coalesced, f16) ==============
    {
        const int xb_i = b * NN + i0, xb_j = b * NN + j0 - 64;
        #pragma unroll
        for (int it = 0; it < 8; ++it) {
            const int idx = tid + it * 512;
            const int row = idx >> 5, c4 = (idx & 31) * 4;
            const int gr  = (row < 64 ? xb_i : xb_j) + row;
            const float4 v = *(const float4*)(x + (size_t)gr * FF + c4);
            half4 hv = {(_Float16)v.x, (_Float16)v.y,
                        (_Float16)v.z, (_Float16)v.w};
            *(half4*)&xlds[row][c4] = hv;
        }
    }
    __syncthreads();

    // ============ phase A: 8 gemm units, ONE per wave (balanced) ==========
    {
        const int xrow0 = ((wv & 2) ? 32 : 0) + ((wv & 4) ? 64 : 0);
        const int htile = wv & 1;
        const int koff  = (wv & 4) ? 0 : FF;
        _Float16* dstbase = (wv & 4) ? &pjlds[xrow0 - 64][0] : &plds[xrow0][0];
        const float* bias = (wv & 4) ? nullptr : b1;

        f32x16 acc = {};
        #pragma unroll
        for (int ks = 0; ks < 8; ++ks) {
            const int k0 = ks * 16 + hi * 8;
            half8 af;
            const float* wb = W1 + (size_t)(koff + k0) * H1 + htile * 32 + m;
            #pragma unroll
            for (int e = 0; e < 8; ++e)
                af[e] = (_Float16)wb[(size_t)e * H1];     // coalesced per e
            const half8 bf = *(const half8*)&xlds[xrow0 + m][k0];
            acc = __builtin_amdgcn_mfma_f32_32x32x16_f16(af, bf, acc, 0, 0, 0);
        }
        _Float16* drow = dstbase + (size_t)m * PAD;       // D col -> LDS row
        #pragma unroll
        for (int q = 0; q < 4; ++q) {                     // packed b64 stores
            half4 hv;
            #pragma unroll
            for (int jj = 0; jj < 4; ++jj) {
                const int r  = q * 4 + jj;                // hl=(r&3)+8(r>>2)+4hi
                const int hg = htile * 32 + 8 * q + 4 * hi + jj;
                float v = acc[r];
                if (bias) v += bias[hg];
                hv[jj] = (_Float16)v;
            }
            *(half4*)(drow + htile * 32 + 8 * q + 4 * hi) = hv;
        }
    }

    // ============ per-wave edge init (weights straight from global) =======
    half8 wa[4];
    #pragma unroll
    for (int c4 = 0; c4 < 4; ++c4)
        #pragma unroll
        for (int e = 0; e < 8; ++e)
            wa[c4][e] = (_Float16)W2[(16 * c4 + hi * 8 + e) * H2 + jn];

    f32x16 ci;
    #pragma unroll
    for (int r = 0; r < 16; ++r) {           // D row mapping [m74/m101]
        const int row = (r & 3) + 8 * (r >> 2) + 4 * hi;
        ci[r] = b2[row];
    }
    f32x2 w32[8];
    #pragma unroll
    for (int q = 0; q < 8; ++q) {
        const int row = ((2 * q) & 3) + 8 * (q >> 1) + 4 * hi;
        w32[q] = (f32x2){W3[row], W3[row + 1]};
    }
    const float b3v = b3[0];

    __syncthreads();   // phase A LDS writes visible to all waves

    const int rowgrp = wv >> 1;
    const int jhalf  = wv & 1;

    const _Float16* pr = &pjlds[jhalf * 32 + jn][hi * 8];
    half8 qj0 = *(const half8*)(pr);
    half8 qj1 = *(const half8*)(pr + 16);
    half8 qj2 = *(const half8*)(pr + 32);
    half8 qj3 = *(const half8*)(pr + 48);

    auto epi = [&](const f32x16& dd) -> float {
        const f32x2 z2 = {0.f, 0.f};
        f32x2 s[4] = {z2, z2, z2, z2};
        #pragma unroll
        for (int q = 0; q < 8; ++q) {
            f32x2 dp = {dd[2 * q], dd[2 * q + 1]};
            dp = __builtin_elementwise_max(dp, z2);
            s[q & 3] = __builtin_elementwise_fma(dp, w32[q], s[q & 3]);
        }
        const f32x2 t01 = s[0] + s[1];
        const f32x2 t23 = s[2] + s[3];
        const f32x2 tt  = t01 + t23;
        float p = tt[0] + tt[1];
        p += __shfl_xor(p, 32);   // lane-halves hold complementary rows
        return p;
    };

    const _Float16* irbase = &plds[rowgrp * 16][hi * 8];
    float* obase = out + (size_t)(b * NN + i0 + rowgrp * 16) * NN
                       + j0 + jhalf * 32 + jn;

    // ============ phase B x REPS (instrumented) ===========================
    #pragma unroll 1
    for (int rep = 0; rep < REPS; ++rep) {
        // opaque per-rep barrier: fresh qj + memory clobber -> no cross-rep
        // CSE of LDS reads, no DCE of idempotent stores (rule #17)
        asm volatile("" : "+v"(qj0), "+v"(qj1), "+v"(qj2), "+v"(qj3) :: "memory");

        // ---- prologue: e(0), dP = mfma(step 0), e(1) ----
        half8 e0 = addrelu8(qj0, *(const half8*)(irbase));
        half8 e1 = addrelu8(qj1, *(const half8*)(irbase + 16));
        half8 e2 = addrelu8(qj2, *(const half8*)(irbase + 32));
        half8 e3 = addrelu8(qj3, *(const half8*)(irbase + 48));
        f32x16 dP;
        dP = __builtin_amdgcn_mfma_f32_32x32x16_f16(wa[0], e0, ci, 0, 0, 0);
        dP = __builtin_amdgcn_mfma_f32_32x32x16_f16(wa[1], e1, dP, 0, 0, 0);
        dP = __builtin_amdgcn_mfma_f32_32x32x16_f16(wa[2], e2, dP, 0, 0, 0);
        dP = __builtin_amdgcn_mfma_f32_32x32x16_f16(wa[3], e3, dP, 0, 0, 0);
        {
            const _Float16* ir = irbase + PAD;
            e0 = addrelu8(qj0, *(const half8*)(ir));
            e1 = addrelu8(qj1, *(const half8*)(ir + 16));
            e2 = addrelu8(qj2, *(const half8*)(ir + 32));
            e3 = addrelu8(qj3, *(const half8*)(ir + 48));
        }
        float pe = 0.f;

        #pragma unroll 2
        for (int t = 1; t < 16; ++t) {
            const int tn = (t < 15) ? t + 1 : 15;
            const _Float16* ir = irbase + tn * PAD;
            const half8 m0 = *(const half8*)(ir);
            const half8 m1 = *(const half8*)(ir + 16);
            const half8 m2 = *(const half8*)(ir + 32);
            const half8 m3 = *(const half8*)(ir + 48);
            f32x16 d;
            d = __builtin_amdgcn_mfma_f32_32x32x16_f16(wa[0], e0, ci, 0, 0, 0);
            d = __builtin_amdgcn_mfma_f32_32x32x16_f16(wa[1], e1, d,  0, 0, 0);
            d = __builtin_amdgcn_mfma_f32_32x32x16_f16(wa[2], e2, d,  0, 0, 0);
            d = __builtin_amdgcn_mfma_f32_32x32x16_f16(wa[3], e3, d,  0, 0, 0);
            const float p = epi(dP);
            if ((t - 1) & 1) {                   // t even: store pair (t-2,t-1)
                const float v = hi ? p : pe;
                obase[(size_t)(t - 2 + hi) * NN] = v + b3v;
            } else {
                pe = p;
            }
            e0 = addrelu8(qj0, m0);
            e1 = addrelu8(qj1, m1);
            e2 = addrelu8(qj2, m2);
            e3 = addrelu8(qj3, m3);
            dP = d;
        }
        // ---- tail: epilogue of step 15, store pair (14,15) ----
        {
            const float p = epi(dP);
            const float v = hi ? p : pe;
            obase[(size_t)(14 + hi) * NN] = v + b3v;
        }
    }
}

extern "C" void kernel_launch(void* const* d_in, const int* in_sizes, int n_in,
                              void* d_out, int out_size, void* d_ws, size_t ws_size,
                              hipStream_t stream) {
    const float* x  = (const float*)d_in[0];
    // d_in[1] = adj (UNUSED by reference), d_in[2] = mask (UNUSED)
    const float* W1 = (const float*)d_in[3];
    const float* b1 = (const float*)d_in[4];
    const float* W2 = (const float*)d_in[5];
    const float* b2 = (const float*)d_in[6];
    const float* W3 = (const float*)d_in[7];
    const float* b3 = (const float*)d_in[8];
    float* out = (float*)d_out;

    // single self-sufficient launch; 512 blocks x 512 threads
    fused_kernel<<<BB * NN * NN / (64 * 64), 512, 0, stream>>>(
        x, W1, b1, W2, b2, W3, b3, out);
}

// Round 15
// 130.586 us; speedup vs baseline: 1.5196x; 1.5196x over previous
//
#include <hip/hip_runtime.h>

#define BB 2
#define NN 1024
#define FF 128
#define H1 64
#define H2 32
#define XPAD 136  // x-row stride in f16 (128+8)
#define PAD 72    // p-row stride in f16 (64+8)
#define REPS 16   // 15 stripped reps + 1 full rep (correct output)

typedef __attribute__((ext_vector_type(4))) _Float16 half4;   // 4 f16 (8B)
typedef __attribute__((ext_vector_type(8))) _Float16 half8;   // 8 f16 (4 VGPR)
typedef __attribute__((ext_vector_type(16))) float f32x16;    // 32x32 MFMA acc
typedef __attribute__((ext_vector_type(2))) float f32x2;      // v_pk_*_f32

// e = relu(a + b) in packed f16: 4x v_pk_add_f16 + 4x v_pk_max_f16
__device__ inline half8 addrelu8(half8 a, half8 b) {
    half8 s = a + b;
    const half8 z = {};
    return __builtin_elementwise_max(s, z);
}

// ---------------------------------------------------------------------------
// ABLATION ROUND (R15). R14 gave B = 11.7us/pass, A+stage = 11.1us, and
// killed the register theory (VGPR=72 under a 256-reg budget; 8 vs 16
// waves/CU identical perf -> issue-bound, not latency-bound). Per-step wall
// ~440cy vs ~130cy of source-countable work: the 3x inflation lives either
// in the epilogue path (f32x2 builtins / __shfl_xor / 64b store addressing)
// or in the LDS+E-build+MFMA core (operand hazards / lowering). This round
// separates them: 15 reps run ONLY the core (ds_read + addrelu + MFMA,
// asm-keepalive on d, per-rep "+v" qj + "memory" clobber vs CSE — rule #17);
// rep 16 is the full R13 phase B so out[] is bit-identical (test passes).
//   B_stripped = (dur - 22.8)/15.
// Branches: dur<=75 -> epilogue is the monster (R16 rewrites it);
//           dur>=150 -> core inflated (R16 bisects addrelu vs LDS).
// R13 (REPS=1) remains the recoverable best at 22.8us.
// ---------------------------------------------------------------------------
__global__ __launch_bounds__(512, 2) void fused_kernel(
    const float* __restrict__ x, const float* __restrict__ W1,
    const float* __restrict__ b1, const float* __restrict__ W2,
    const float* __restrict__ b2, const float* __restrict__ W3,
    const float* __restrict__ b3, float* __restrict__ out)
{
    __shared__ __align__(16) _Float16 xlds[128][XPAD];  // 34.8 KB staged x
    __shared__ __align__(16) _Float16 plds[64][PAD];    // 9.2 KB pib rows
    __shared__ __align__(16) _Float16 pjlds[64][PAD];   // 9.2 KB pj rows

    const int tid  = threadIdx.x;
    const int lane = tid & 63;
    const int wv   = tid >> 6;                // 0..7
    const int bid  = blockIdx.x;

    const int b   = bid >> 8;                 // 256 blocks per batch
    const int rem = bid & 255;
    const int i0  = (rem >> 4) * 64;          // 16 i-tiles (64 rows each)
    const int j0  = (rem & 15) * 64;          // 16 j-tiles (64 cols each)
    const int jn  = lane & 31;                // m/n lane index
    const int hi  = lane >> 5;                // k-group half
    const int m   = jn;

    // ============ stage: 128 x-rows -> xlds (coalesced, f16) ==============
    {
        const int xb_i = b * NN + i0, xb_j = b * NN + j0 - 64;
        #pragma unroll
        for (int it = 0; it < 8; ++it) {
            const int idx = tid + it * 512;
            const int row = idx >> 5, c4 = (idx & 31) * 4;
            const int gr  = (row < 64 ? xb_i : xb_j) + row;
            const float4 v = *(const float4*)(x + (size_t)gr * FF + c4);
            half4 hv = {(_Float16)v.x, (_Float16)v.y,
                        (_Float16)v.z, (_Float16)v.w};
            *(half4*)&xlds[row][c4] = hv;
        }
    }
    __syncthreads();

    // ============ phase A: 8 gemm units, ONE per wave (balanced) ==========
    {
        const int xrow0 = ((wv & 2) ? 32 : 0) + ((wv & 4) ? 64 : 0);
        const int htile = wv & 1;
        const int koff  = (wv & 4) ? 0 : FF;
        _Float16* dstbase = (wv & 4) ? &pjlds[xrow0 - 64][0] : &plds[xrow0][0];
        const float* bias = (wv & 4) ? nullptr : b1;

        f32x16 acc = {};
        #pragma unroll
        for (int ks = 0; ks < 8; ++ks) {
            const int k0 = ks * 16 + hi * 8;
            half8 af;
            const float* wb = W1 + (size_t)(koff + k0) * H1 + htile * 32 + m;
            #pragma unroll
            for (int e = 0; e < 8; ++e)
                af[e] = (_Float16)wb[(size_t)e * H1];     // coalesced per e
            const half8 bf = *(const half8*)&xlds[xrow0 + m][k0];
            acc = __builtin_amdgcn_mfma_f32_32x32x16_f16(af, bf, acc, 0, 0, 0);
        }
        _Float16* drow = dstbase + (size_t)m * PAD;       // D col -> LDS row
        #pragma unroll
        for (int q = 0; q < 4; ++q) {                     // packed b64 stores
            half4 hv;
            #pragma unroll
            for (int jj = 0; jj < 4; ++jj) {
                const int r  = q * 4 + jj;                // hl=(r&3)+8(r>>2)+4hi
                const int hg = htile * 32 + 8 * q + 4 * hi + jj;
                float v = acc[r];
                if (bias) v += bias[hg];
                hv[jj] = (_Float16)v;
            }
            *(half4*)(drow + htile * 32 + 8 * q + 4 * hi) = hv;
        }
    }

    // ============ per-wave edge init (weights straight from global) =======
    half8 wa[4];
    #pragma unroll
    for (int c4 = 0; c4 < 4; ++c4)
        #pragma unroll
        for (int e = 0; e < 8; ++e)
            wa[c4][e] = (_Float16)W2[(16 * c4 + hi * 8 + e) * H2 + jn];

    f32x16 ci;
    #pragma unroll
    for (int r = 0; r < 16; ++r) {           // D row mapping [m74/m101]
        const int row = (r & 3) + 8 * (r >> 2) + 4 * hi;
        ci[r] = b2[row];
    }
    f32x2 w32[8];
    #pragma unroll
    for (int q = 0; q < 8; ++q) {
        const int row = ((2 * q) & 3) + 8 * (q >> 1) + 4 * hi;
        w32[q] = (f32x2){W3[row], W3[row + 1]};
    }
    const float b3v = b3[0];

    __syncthreads();   // phase A LDS writes visible to all waves

    const int rowgrp = wv >> 1;
    const int jhalf  = wv & 1;

    const _Float16* pr = &pjlds[jhalf * 32 + jn][hi * 8];
    half8 qj0 = *(const half8*)(pr);
    half8 qj1 = *(const half8*)(pr + 16);
    half8 qj2 = *(const half8*)(pr + 32);
    half8 qj3 = *(const half8*)(pr + 48);

    auto epi = [&](const f32x16& dd) -> float {
        const f32x2 z2 = {0.f, 0.f};
        f32x2 s[4] = {z2, z2, z2, z2};
        #pragma unroll
        for (int q = 0; q < 8; ++q) {
            f32x2 dp = {dd[2 * q], dd[2 * q + 1]};
            dp = __builtin_elementwise_max(dp, z2);
            s[q & 3] = __builtin_elementwise_fma(dp, w32[q], s[q & 3]);
        }
        const f32x2 t01 = s[0] + s[1];
        const f32x2 t23 = s[2] + s[3];
        const f32x2 tt  = t01 + t23;
        float p = tt[0] + tt[1];
        p += __shfl_xor(p, 32);   // lane-halves hold complementary rows
        return p;
    };

    const _Float16* irbase = &plds[rowgrp * 16][hi * 8];
    float* obase = out + (size_t)(b * NN + i0 + rowgrp * 16) * NN
                       + j0 + jhalf * 32 + jn;

    // ============ phase B: 15 stripped reps + 1 full rep ==================
    #pragma unroll 1
    for (int rep = 0; rep < REPS; ++rep) {
        // opaque per-rep barrier: fresh qj + memory clobber (rule #17)
        asm volatile("" : "+v"(qj0), "+v"(qj1), "+v"(qj2), "+v"(qj3) :: "memory");

        if (rep < REPS - 1) {
            // ---- STRIPPED: LDS reads + E-build + MFMA chain only ----
            #pragma unroll 1
            for (int t = 0; t < 16; ++t) {
                const _Float16* ir = irbase + t * PAD;
                const half8 c0 = *(const half8*)(ir);
                const half8 c1 = *(const half8*)(ir + 16);
                const half8 c2 = *(const half8*)(ir + 32);
                const half8 c3 = *(const half8*)(ir + 48);
                const half8 e0 = addrelu8(qj0, c0);
                const half8 e1 = addrelu8(qj1, c1);
                const half8 e2 = addrelu8(qj2, c2);
                const half8 e3 = addrelu8(qj3, c3);
                f32x16 d;
                d = __builtin_amdgcn_mfma_f32_32x32x16_f16(wa[0], e0, ci, 0, 0, 0);
                d = __builtin_amdgcn_mfma_f32_32x32x16_f16(wa[1], e1, d,  0, 0, 0);
                d = __builtin_amdgcn_mfma_f32_32x32x16_f16(wa[2], e2, d,  0, 0, 0);
                d = __builtin_amdgcn_mfma_f32_32x32x16_f16(wa[3], e3, d,  0, 0, 0);
                // keepalive: consuming 4 elems keeps the whole chain live
                asm volatile("" :: "v"(d[0]), "v"(d[5]), "v"(d[10]), "v"(d[15]));
            }
        } else {
            // ---- FULL R13 phase B (writes the correct output) ----
            half8 e0 = addrelu8(qj0, *(const half8*)(irbase));
            half8 e1 = addrelu8(qj1, *(const half8*)(irbase + 16));
            half8 e2 = addrelu8(qj2, *(const half8*)(irbase + 32));
            half8 e3 = addrelu8(qj3, *(const half8*)(irbase + 48));
            f32x16 dP;
            dP = __builtin_amdgcn_mfma_f32_32x32x16_f16(wa[0], e0, ci, 0, 0, 0);
            dP = __builtin_amdgcn_mfma_f32_32x32x16_f16(wa[1], e1, dP, 0, 0, 0);
            dP = __builtin_amdgcn_mfma_f32_32x32x16_f16(wa[2], e2, dP, 0, 0, 0);
            dP = __builtin_amdgcn_mfma_f32_32x32x16_f16(wa[3], e3, dP, 0, 0, 0);
            {
                const _Float16* ir = irbase + PAD;
                e0 = addrelu8(qj0, *(const half8*)(ir));
                e1 = addrelu8(qj1, *(const half8*)(ir + 16));
                e2 = addrelu8(qj2, *(const half8*)(ir + 32));
                e3 = addrelu8(qj3, *(const half8*)(ir + 48));
            }
            float pe = 0.f;

            #pragma unroll 2
            for (int t = 1; t < 16; ++t) {
                const int tn = (t < 15) ? t + 1 : 15;
                const _Float16* ir = irbase + tn * PAD;
                const half8 m0 = *(const half8*)(ir);
                const half8 m1 = *(const half8*)(ir + 16);
                const half8 m2 = *(const half8*)(ir + 32);
                const half8 m3 = *(const half8*)(ir + 48);
                f32x16 d;
                d = __builtin_amdgcn_mfma_f32_32x32x16_f16(wa[0], e0, ci, 0, 0, 0);
                d = __builtin_amdgcn_mfma_f32_32x32x16_f16(wa[1], e1, d,  0, 0, 0);
                d = __builtin_amdgcn_mfma_f32_32x32x16_f16(wa[2], e2, d,  0, 0, 0);
                d = __builtin_amdgcn_mfma_f32_32x32x16_f16(wa[3], e3, d,  0, 0, 0);
                const float p = epi(dP);
                if ((t - 1) & 1) {                   // store pair (t-2, t-1)
                    const float v = hi ? p : pe;
                    obase[(size_t)(t - 2 + hi) * NN] = v + b3v;
                } else {
                    pe = p;
                }
                e0 = addrelu8(qj0, m0);
                e1 = addrelu8(qj1, m1);
                e2 = addrelu8(qj2, m2);
                e3 = addrelu8(qj3, m3);
                dP = d;
            }
            {
                const float p = epi(dP);
                const float v = hi ? p : pe;
                obase[(size_t)(14 + hi) * NN] = v + b3v;
            }
        }
    }
}

extern "C" void kernel_launch(void* const* d_in, const int* in_sizes, int n_in,
                              void* d_out, int out_size, void* d_ws, size_t ws_size,
                              hipStream_t stream) {
    const float* x  = (const float*)d_in[0];
    // d_in[1] = adj (UNUSED by reference), d_in[2] = mask (UNUSED)
    const float* W1 = (const float*)d_in[3];
    const float* b1 = (const float*)d_in[4];
    const float* W2 = (const float*)d_in[5];
    const float* b2 = (const float*)d_in[6];
    const float* W3 = (const float*)d_in[7];
    const float* b3 = (const float*)d_in[8];
    float* out = (float*)d_out;

    // single self-sufficient launch; 512 blocks x 512 threads
    fused_kernel<<<BB * NN * NN / (64 * 64), 512, 0, stream>>>(
        x, W1, b1, W2, b2, W3, b3, out);
}

// Round 16
// 23.483 us; speedup vs baseline: 8.4504x; 5.5609x over previous
//
#include <hip/hip_runtime.h>

#define BB 2
#define NN 1024
#define FF 128
#define H1 64
#define H2 32
#define XPAD 136  // x-row stride in f16 (128+8)
#define PAD 72    // p-row stride in f16 (64+8)

typedef __attribute__((ext_vector_type(4))) _Float16 half4;   // 4 f16 (8B)
typedef __attribute__((ext_vector_type(8))) _Float16 half8;   // 8 f16 (4 VGPR)
typedef __attribute__((ext_vector_type(16))) float f32x16;    // 32x32 MFMA acc
typedef __attribute__((ext_vector_type(2))) float f32x2;      // v_pk_*_f32

// e = relu(a + b) in packed f16: 4x v_pk_add_f16 + 4x v_pk_max_f16
__device__ inline half8 addrelu8(half8 a, half8 b) {
    half8 s = a + b;
    const half8 z = {};
    return __builtin_elementwise_max(s, z);
}

// ---------------------------------------------------------------------------
// ZERO-SYNC full fusion, v7. R14/R15 attribution: A+stage = 11.1us (vs ~3
// modeled), B = 11.7us (core ~7.2 overstated by a keepalive artifact, epi
// ~4.5). This round attacks A+stage's cold-memory cascade (caches are
// re-poisoned by the harness before every run):
//  (1) W1 fragment loads for ks=0..3 hoisted ABOVE the x-stage -> their cold
//      ~900cy latency overlaps staging + barrier instead of serializing
//      after it (32 f32 regs; total ~110 VGPR, under the 128 cap).
//  (2) Bijective XCD-chunked blockIdx swizzle (512%8==0): the 16 blocks
//      sharing an i-tile land on one XCD's L2 (T1).
//  (3) __launch_bounds__(512,4): cap 128 VGPR (R14: allocator wants 72;
//      (512,2)'s 256 budget was vacuous and risks pressure balloon).
// Phase B byte-identical to R13 (22.8us best). No arithmetic reordering ->
// absmax bit-identical.
// ---------------------------------------------------------------------------
__global__ __launch_bounds__(512, 4) void fused_kernel(
    const float* __restrict__ x, const float* __restrict__ W1,
    const float* __restrict__ b1, const float* __restrict__ W2,
    const float* __restrict__ b2, const float* __restrict__ W3,
    const float* __restrict__ b3, float* __restrict__ out)
{
    __shared__ __align__(16) _Float16 xlds[128][XPAD];  // 34.8 KB staged x
    __shared__ __align__(16) _Float16 plds[64][PAD];    // 9.2 KB pib rows
    __shared__ __align__(16) _Float16 pjlds[64][PAD];   // 9.2 KB pj rows

    const int tid  = threadIdx.x;
    const int lane = tid & 63;
    const int wv   = tid >> 6;                // 0..7
    // XCD-chunked bijective swizzle: XCD c (bid%8) owns contiguous s-range
    // [c*64, (c+1)*64) -> 4 i-tiles per XCD L2 (i-row x reads XCD-local).
    const int bid  = ((blockIdx.x & 7) << 6) | (blockIdx.x >> 3);

    const int b   = bid >> 8;                 // 256 blocks per batch
    const int rem = bid & 255;
    const int i0  = (rem >> 4) * 64;          // 16 i-tiles (64 rows each)
    const int j0  = (rem & 15) * 64;          // 16 j-tiles (64 cols each)
    const int jn  = lane & 31;                // m/n lane index
    const int hi  = lane >> 5;                // k-group half
    const int m   = jn;

    // ---- per-wave phase-A geometry (needed for the hoist) ----
    const int xrow0 = ((wv & 2) ? 32 : 0) + ((wv & 4) ? 64 : 0);
    const int htile = wv & 1;
    const int koff  = (wv & 4) ? 0 : FF;

    // ============ HOIST: W1 ks=0..3 raw loads (cold latency overlap) ======
    float wraw[4][8];
    #pragma unroll
    for (int ks = 0; ks < 4; ++ks) {
        const int k0 = ks * 16 + hi * 8;
        const float* wb = W1 + (size_t)(koff + k0) * H1 + htile * 32 + m;
        #pragma unroll
        for (int e = 0; e < 8; ++e)
            wraw[ks][e] = wb[(size_t)e * H1];             // coalesced per e
    }

    // ============ stage: 128 x-rows -> xlds (coalesced, f16) ==============
    // rows 0..63 = i-rows i0..i0+63; rows 64..127 = j-rows j0..j0+63.
    {
        const int xb_i = b * NN + i0, xb_j = b * NN + j0 - 64;
        #pragma unroll
        for (int it = 0; it < 8; ++it) {
            const int idx = tid + it * 512;
            const int row = idx >> 5, c4 = (idx & 31) * 4;
            const int gr  = (row < 64 ? xb_i : xb_j) + row;
            const float4 v = *(const float4*)(x + (size_t)gr * FF + c4);
            half4 hv = {(_Float16)v.x, (_Float16)v.y,
                        (_Float16)v.z, (_Float16)v.w};
            *(half4*)&xlds[row][c4] = hv;
        }
    }
    __syncthreads();

    // ============ phase A: 8 gemm units, ONE per wave (balanced) ==========
    //   wv0/1: pib rows  0-31 (htile 0/1)   wv2/3: pib rows 32-63
    //   wv4/5: pj  rows  0-31               wv6/7: pj  rows 32-63
    {
        _Float16* dstbase = (wv & 4) ? &pjlds[xrow0 - 64][0] : &plds[xrow0][0];
        const float* bias = (wv & 4) ? nullptr : b1;

        f32x16 acc = {};
        #pragma unroll
        for (int ks = 0; ks < 8; ++ks) {
            const int k0 = ks * 16 + hi * 8;
            half8 af;
            if (ks < 4) {                     // hoisted (already in regs)
                #pragma unroll
                for (int e = 0; e < 8; ++e)
                    af[e] = (_Float16)wraw[ks][e];
            } else {                          // loaded here (L2-warm by now)
                const float* wb = W1 + (size_t)(koff + k0) * H1 + htile * 32 + m;
                #pragma unroll
                for (int e = 0; e < 8; ++e)
                    af[e] = (_Float16)wb[(size_t)e * H1];
            }
            const half8 bf = *(const half8*)&xlds[xrow0 + m][k0];
            acc = __builtin_amdgcn_mfma_f32_32x32x16_f16(af, bf, acc, 0, 0, 0);
        }
        _Float16* drow = dstbase + (size_t)m * PAD;       // D col -> LDS row
        #pragma unroll
        for (int q = 0; q < 4; ++q) {                     // packed b64 stores
            half4 hv;
            #pragma unroll
            for (int jj = 0; jj < 4; ++jj) {
                const int r  = q * 4 + jj;                // hl=(r&3)+8(r>>2)+4hi
                const int hg = htile * 32 + 8 * q + 4 * hi + jj;
                float v = acc[r];
                if (bias) v += bias[hg];
                hv[jj] = (_Float16)v;
            }
            *(half4*)(drow + htile * 32 + 8 * q + 4 * hi) = hv;
        }
    }

    // ============ per-wave edge init (weights straight from global) =======
    half8 wa[4];
    #pragma unroll
    for (int c4 = 0; c4 < 4; ++c4)
        #pragma unroll
        for (int e = 0; e < 8; ++e)
            wa[c4][e] = (_Float16)W2[(16 * c4 + hi * 8 + e) * H2 + jn];

    f32x16 ci;
    #pragma unroll
    for (int r = 0; r < 16; ++r) {           // D row mapping [m74/m101]
        const int row = (r & 3) + 8 * (r >> 2) + 4 * hi;
        ci[r] = b2[row];
    }
    // W3 paired for the packed epilogue (R10 layout, verified)
    f32x2 w32[8];
    #pragma unroll
    for (int q = 0; q < 8; ++q) {
        const int row = ((2 * q) & 3) + 8 * (q >> 1) + 4 * hi;
        w32[q] = (f32x2){W3[row], W3[row + 1]};
    }
    const float b3v = b3[0];

    __syncthreads();   // phase A LDS writes visible to all waves

    // wave's phase-B assignment: row-group (wv>>1)*16, j-half (wv&1)*32
    const int rowgrp = wv >> 1;
    const int jhalf  = wv & 1;

    // B-frags (pj side) from LDS: row jhalf*32+jn, k-slices 16c + hi*8
    const _Float16* pr = &pjlds[jhalf * 32 + jn][hi * 8];
    const half8 qj0 = *(const half8*)(pr);
    const half8 qj1 = *(const half8*)(pr + 16);
    const half8 qj2 = *(const half8*)(pr + 32);
    const half8 qj3 = *(const half8*)(pr + 48);

    // R10 packed epilogue (incl. cross-half shfl)
    auto epi = [&](const f32x16& dd) -> float {
        const f32x2 z2 = {0.f, 0.f};
        f32x2 s[4] = {z2, z2, z2, z2};
        #pragma unroll
        for (int q = 0; q < 8; ++q) {
            f32x2 dp = {dd[2 * q], dd[2 * q + 1]};
            dp = __builtin_elementwise_max(dp, z2);
            s[q & 3] = __builtin_elementwise_fma(dp, w32[q], s[q & 3]);
        }
        const f32x2 t01 = s[0] + s[1];
        const f32x2 t23 = s[2] + s[3];
        const f32x2 tt  = t01 + t23;
        float p = tt[0] + tt[1];
        p += __shfl_xor(p, 32);   // lane-halves hold complementary rows
        return p;
    };

    // ============ phase B: software-pipelined 16 row-steps (R13) ==========
    const _Float16* irbase = &plds[rowgrp * 16][hi * 8];
    float* obase = out + (size_t)(b * NN + i0 + rowgrp * 16) * NN
                       + j0 + jhalf * 32 + jn;

    // ---- prologue: e(0), dP = mfma(step 0), e(1) ----
    half8 e0 = addrelu8(qj0, *(const half8*)(irbase));
    half8 e1 = addrelu8(qj1, *(const half8*)(irbase + 16));
    half8 e2 = addrelu8(qj2, *(const half8*)(irbase + 32));
    half8 e3 = addrelu8(qj3, *(const half8*)(irbase + 48));
    f32x16 dP;
    dP = __builtin_amdgcn_mfma_f32_32x32x16_f16(wa[0], e0, ci, 0, 0, 0);
    dP = __builtin_amdgcn_mfma_f32_32x32x16_f16(wa[1], e1, dP, 0, 0, 0);
    dP = __builtin_amdgcn_mfma_f32_32x32x16_f16(wa[2], e2, dP, 0, 0, 0);
    dP = __builtin_amdgcn_mfma_f32_32x32x16_f16(wa[3], e3, dP, 0, 0, 0);
    {
        const _Float16* ir = irbase + PAD;
        e0 = addrelu8(qj0, *(const half8*)(ir));
        e1 = addrelu8(qj1, *(const half8*)(ir + 16));
        e2 = addrelu8(qj2, *(const half8*)(ir + 32));
        e3 = addrelu8(qj3, *(const half8*)(ir + 48));
    }
    float pe = 0.f;

    #pragma unroll 2
    for (int t = 1; t < 16; ++t) {
        // 1. prefetch LDS row for step t+1
        const int tn = (t < 15) ? t + 1 : 15;
        const _Float16* ir = irbase + tn * PAD;
        const half8 m0 = *(const half8*)(ir);
        const half8 m1 = *(const half8*)(ir + 16);
        const half8 m2 = *(const half8*)(ir + 32);
        const half8 m3 = *(const half8*)(ir + 48);
        // 2. MFMA chain of step t on e (built last iteration)
        f32x16 d;
        d = __builtin_amdgcn_mfma_f32_32x32x16_f16(wa[0], e0, ci, 0, 0, 0);
        d = __builtin_amdgcn_mfma_f32_32x32x16_f16(wa[1], e1, d,  0, 0, 0);
        d = __builtin_amdgcn_mfma_f32_32x32x16_f16(wa[2], e2, d,  0, 0, 0);
        d = __builtin_amdgcn_mfma_f32_32x32x16_f16(wa[3], e3, d,  0, 0, 0);
        // 3. epilogue of step t-1 (independent of the chain above)
        const float p = epi(dP);
        if ((t - 1) & 1) {                   // t even: store pair (t-2, t-1)
            const float v = hi ? p : pe;     // hi half stores the odd row
            obase[(size_t)(t - 2 + hi) * NN] = v + b3v;
        } else {
            pe = p;
        }
        // 4. build E for step t+1 (independent of the chain above)
        e0 = addrelu8(qj0, m0);
        e1 = addrelu8(qj1, m1);
        e2 = addrelu8(qj2, m2);
        e3 = addrelu8(qj3, m3);
        dP = d;
    }
    // ---- tail: epilogue of step 15, store pair (14,15) ----
    {
        const float p = epi(dP);
        const float v = hi ? p : pe;
        obase[(size_t)(14 + hi) * NN] = v + b3v;
    }
}

extern "C" void kernel_launch(void* const* d_in, const int* in_sizes, int n_in,
                              void* d_out, int out_size, void* d_ws, size_t ws_size,
                              hipStream_t stream) {
    const float* x  = (const float*)d_in[0];
    // d_in[1] = adj (UNUSED by reference), d_in[2] = mask (UNUSED)
    const float* W1 = (const float*)d_in[3];
    const float* b1 = (const float*)d_in[4];
    const float* W2 = (const float*)d_in[5];
    const float* b2 = (const float*)d_in[6];
    const float* W3 = (const float*)d_in[7];
    const float* b3 = (const float*)d_in[8];
    float* out = (float*)d_out;

    // single self-sufficient launch; 512 blocks x 512 threads
    fused_kernel<<<BB * NN * NN / (64 * 64), 512, 0, stream>>>(
        x, W1, b1, W2, b2, W3, b3, out);
}